// Round 17
// baseline (3435.899 us; speedup 1.0000x reference)
//
#include <hip/hip_runtime.h>
#include <stdint.h>

#define NROWS 16384
#define NCODES 16384
#define DIM 256
#define CAP 128

typedef unsigned short ushort_t;
typedef unsigned long long ull_t;
typedef __attribute__((ext_vector_type(8))) short bf16x8;
typedef __attribute__((ext_vector_type(4))) float f32x4;
typedef __attribute__((address_space(1))) const void gas_t;
typedef __attribute__((address_space(3))) void las_t;

// ---------------- which input is z? (z ~ N(0,1), emb ~ N(0,1)/16384) ----------------
__global__ __launch_bounds__(256)
void vq_which_kernel(const float* __restrict__ p0, const float* __restrict__ p1,
                     int* __restrict__ flag)
{
    __shared__ float red[256];
    const int tid = threadIdx.x;
    float s = 0.f;
    for (int t = tid; t < 4096; t += 256) s += fabsf(p0[t]) - fabsf(p1[t]);
    red[tid] = s;
    __syncthreads();
    for (int k = 128; k > 0; k >>= 1) {
        if (tid < k) red[tid] += red[tid + k];
        __syncthreads();
    }
    if (tid == 0) flag[0] = (red[0] >= 0.f) ? 0 : 1;   // 0: p0 is z
}

// numpy pairwise fp32 sum of squares of a 256-float row (exact numpy order).
__device__ __forceinline__ float np_pairwise_sumsq256(const float* __restrict__ a)
{
    float H[2];
    #pragma unroll
    for (int h = 0; h < 2; ++h) {
        const float* p = a + h * 128;
        float r[8];
        #pragma unroll
        for (int j = 0; j < 8; ++j) r[j] = __fmul_rn(p[j], p[j]);
        for (int i = 8; i < 128; i += 8) {
            #pragma unroll
            for (int j = 0; j < 8; ++j)
                r[j] = __fadd_rn(r[j], __fmul_rn(p[i + j], p[i + j]));
        }
        H[h] = __fadd_rn(__fadd_rn(__fadd_rn(r[0], r[1]), __fadd_rn(r[2], r[3])),
                         __fadd_rn(__fadd_rn(r[4], r[5]), __fadd_rn(r[6], r[7])));
    }
    return __fadd_rn(H[0], H[1]);
}

// ---------------- per-row ||z||^2 in exact numpy order ----------------
#define AR_ROWS 32
#define AR_STR 260
__global__ __launch_bounds__(256)
void vq_arow_kernel(const float* __restrict__ p0, const float* __restrict__ p1,
                    const int* __restrict__ flag, float* __restrict__ arow_g)
{
    const float* __restrict__ Z = (flag[0] == 0) ? p0 : p1;
    __shared__ float ls[AR_ROWS * AR_STR];
    const int tid = threadIdx.x;
    const int row0 = blockIdx.x * AR_ROWS;
    #pragma unroll
    for (int q = 0; q < 8; ++q) {
        int f4 = tid + 256 * q;
        int r = f4 >> 6;
        int c = (f4 & 63) << 2;
        *(float4*)&ls[r * AR_STR + c] =
            *(const float4*)&Z[(size_t)(row0 + r) * DIM + c];
    }
    __syncthreads();
    if (tid < AR_ROWS) arow_g[row0 + tid] = np_pairwise_sumsq256(&ls[tid * AR_STR]);
}

// ---------------- reset: gmin=FLT_MAX, cnt=0, emax=0 ----------------
__global__ __launch_bounds__(256)
void vq_reset_kernel(unsigned* __restrict__ gmin, unsigned* __restrict__ cnt,
                     unsigned* __restrict__ emax)
{
    int i = blockIdx.x * 256 + threadIdx.x;
    if (i < NROWS) { gmin[i] = 0x7F7FFFFFu; cnt[i] = 0u; }
    if (i == 0) emax[0] = 0u;
}

// ---------------- fp32 -> bf16 (RNE) copies of both inputs ----------------
__device__ __forceinline__ ushort_t f2bf(float x)
{
    unsigned u = __float_as_uint(x);
    return (ushort_t)((u + 0x7FFFu + ((u >> 16) & 1u)) >> 16);
}
__global__ __launch_bounds__(256)
void vq_convert_kernel(const float* __restrict__ p0, const float* __restrict__ p1,
                       const int* __restrict__ flag,
                       ushort_t* __restrict__ zbf, ushort_t* __restrict__ ebf)
{
    const float* __restrict__ Z = (flag[0] == 0) ? p0 : p1;
    const float* __restrict__ E = (flag[0] == 0) ? p1 : p0;
    size_t i = ((size_t)blockIdx.x * 256 + threadIdx.x) * 4;
    if (i >= (size_t)NROWS * DIM) return;
    float4 z4 = *(const float4*)&Z[i];
    float4 e4 = *(const float4*)&E[i];
    ushort4 zo = { f2bf(z4.x), f2bf(z4.y), f2bf(z4.z), f2bf(z4.w) };
    ushort4 eo = { f2bf(e4.x), f2bf(e4.y), f2bf(e4.z), f2bf(e4.w) };
    *(ushort4*)&zbf[i] = zo;
    *(ushort4*)&ebf[i] = eo;
}

// ---------------- max code L2 norm (for the rigorous margin) ----------------
__global__ __launch_bounds__(256)
void vq_enorm_kernel(const float* __restrict__ p0, const float* __restrict__ p1,
                     const int* __restrict__ flag, unsigned* __restrict__ emax)
{
    const float* __restrict__ E = (flag[0] == 0) ? p1 : p0;
    int wave = (blockIdx.x * blockDim.x + threadIdx.x) >> 6;
    int lane = threadIdx.x & 63;
    if (wave >= NCODES) return;
    float4 v = *(const float4*)&E[(size_t)wave * DIM + lane * 4];
    float s = v.x * v.x + v.y * v.y + v.z * v.z + v.w * v.w;
    #pragma unroll
    for (int off = 32; off > 0; off >>= 1) s += __shfl_down(s, off);
    if (lane == 0) atomicMax(emax, __float_as_uint(sqrtf(s)));
}

// ---------------- phase 1: bf16 MFMA distance sweep + candidate capture ------
// ROUND-17: 256x128 block, 4 waves, each wave owns 64 rows (acc[4][8]) ->
// 12 ds_read_b128 per 32 MFMAs (was 10 per 16). K staged as 8 ascending
// slices of 32 bf16, DOUBLE-BUFFERED global_load_lds DMA (linear LDS, linear
// source, NO swizzle): K-step rows are 64 B so bank-group = (row&1)*4+chunk,
// uniformly 8 lanes/group for both A and B reads = b128 minimum.
// Schedule per step: stage(next buf) -> compute(cur) -> barrier (round-9
// verified pattern). K-order: 8 ascending K=32 slices == rounds 13/15/16 ->
// every approx distance BIT-IDENTICAL; capture math formulas unchanged
// (mechanically widened to 16 outputs/lane, processed per-rf).
// A/B frag: lane&15 = row/col, k = (lane>>4)*8+elem. C/D: col=lane&15,
// row=(lane>>4)*4+reg [verified m89 + rounds 13/15/16 absmax 0.0].
// SPILL GUARD: step/rf loops `#pragma unroll 1`; watch WRITE_SIZE for spill.
__global__ __launch_bounds__(256, 1)
void vq_mfma_kernel(const ushort_t* __restrict__ zbf, const ushort_t* __restrict__ ebf,
                    const float* __restrict__ arow_g, const unsigned* __restrict__ emax,
                    unsigned* __restrict__ gmin, unsigned* __restrict__ cnt,
                    ushort_t* __restrict__ cand)
{
    __shared__ ushort_t zs[2][256 * 32];   // 16 KB per buffer
    __shared__ ushort_t es[2][128 * 32];   // 8 KB per buffer
    const int tid = threadIdx.x;
    const int row0 = blockIdx.x * 256;
    const int c0   = blockIdx.y * 128;

    const int w  = tid >> 6;
    const int l  = tid & 63;
    const int lr = l & 15;
    const int lk = l >> 4;

    // DMA group = 1 KB = 16 rows x 64 B; lane l -> row (l>>2), 16B chunk (l&3)
    const int drow = l >> 2;
    const int dchk = (l & 3) * 8;   // ushort offset in row

#define VQ_STAGE(BB, TT)                                                     \
    do {                                                                     \
        _Pragma("unroll")                                                    \
        for (int q_ = 0; q_ < 4; ++q_) {                                     \
            const int g_ = (w << 2) + q_;                                    \
            __builtin_amdgcn_global_load_lds(                                \
                (gas_t*)(zbf + (size_t)(row0 + (g_ << 4) + drow) * DIM       \
                          + (TT) * 32 + dchk),                               \
                (las_t*)&zs[BB][g_ << 9], 16, 0, 0);                         \
        }                                                                    \
        _Pragma("unroll")                                                    \
        for (int q_ = 0; q_ < 2; ++q_) {                                     \
            const int g_ = (w << 1) + q_;                                    \
            __builtin_amdgcn_global_load_lds(                                \
                (gas_t*)(ebf + (size_t)(c0 + (g_ << 4) + drow) * DIM         \
                          + (TT) * 32 + dchk),                               \
                (las_t*)&es[BB][g_ << 9], 16, 0, 0);                         \
        }                                                                    \
    } while (0)

#define VQ_COMPUTE(BB)                                                       \
    do {                                                                     \
        bf16x8 a_[4];                                                        \
        _Pragma("unroll")                                                    \
        for (int rf = 0; rf < 4; ++rf)                                       \
            a_[rf] = *(const bf16x8*)                                        \
                &zs[BB][((w << 6) + (rf << 4) + lr) * 32 + lk * 8];          \
        _Pragma("unroll")                                                    \
        for (int cf = 0; cf < 8; ++cf) {                                     \
            bf16x8 b_ = *(const bf16x8*)&es[BB][((cf << 4) + lr) * 32 + lk * 8]; \
            _Pragma("unroll")                                                \
            for (int rf = 0; rf < 4; ++rf)                                   \
                acc[rf][cf] = __builtin_amdgcn_mfma_f32_16x16x32_bf16(       \
                    a_[rf], b_, acc[rf][cf], 0, 0, 0);                       \
        }                                                                    \
    } while (0)

    f32x4 acc[4][8];
    #pragma unroll
    for (int rf = 0; rf < 4; ++rf)
        #pragma unroll
        for (int cf = 0; cf < 8; ++cf) acc[rf][cf] = (f32x4){0.f, 0.f, 0.f, 0.f};

    // prologue: stage K-slice 0 into buf0
    VQ_STAGE(0, 0);
    __syncthreads();

    #pragma unroll 1
    for (int t2 = 0; t2 < 4; ++t2) {
        const int t0 = t2 * 2;
        // step A: stage t0+1 -> buf1, compute buf0
        VQ_STAGE(1, t0 + 1);
        VQ_COMPUTE(0);
        __syncthreads();
        // step B: stage t0+2 -> buf0, compute buf1
        if (t0 + 2 < 8) VQ_STAGE(0, t0 + 2);
        VQ_COMPUTE(1);
        __syncthreads();
    }

    const float emaxv = __uint_as_float(emax[0]);

    #pragma unroll 1
    for (int rf = 0; rf < 4; ++rf) {
        float Av4[4], rm4[4];
        #pragma unroll
        for (int reg = 0; reg < 4; ++reg)
            Av4[reg] = arow_g[row0 + (w << 6) + (rf << 4) + lk * 4 + reg];
        #pragma unroll
        for (int reg = 0; reg < 4; ++reg) {
            float mn = 3.4e38f;
            #pragma unroll
            for (int cf = 0; cf < 8; ++cf) {
                float d = __fsub_rn(Av4[reg], __fmul_rn(2.0f, acc[rf][cf][reg]));
                acc[rf][cf][reg] = d;
                mn = fminf(mn, d);
            }
            rm4[reg] = mn;
        }
        #pragma unroll
        for (int m_ = 1; m_ < 16; m_ <<= 1)
            #pragma unroll
            for (int reg = 0; reg < 4; ++reg)
                rm4[reg] = fminf(rm4[reg], __shfl_xor(rm4[reg], m_));

        if (lr == 0) {
            #pragma unroll
            for (int reg = 0; reg < 4; ++reg) {
                int row = row0 + (w << 6) + (rf << 4) + lk * 4 + reg;
                atomicMin(&gmin[row], __float_as_uint(rm4[reg]));
            }
        }

        #pragma unroll
        for (int reg = 0; reg < 4; ++reg) {
            int row = row0 + (w << 6) + (rf << 4) + lk * 4 + reg;
            float g = __uint_as_float(gmin[row]);   // stale => larger => safe
            float m = 0.036f * sqrtf(Av4[reg]) * emaxv + 1.5e-4f;
            float th = fminf(g, rm4[reg]) + m;
            #pragma unroll
            for (int cf = 0; cf < 8; ++cf) {
                if (acc[rf][cf][reg] <= th) {
                    unsigned slot = atomicAdd(&cnt[row], 1u);
                    if (slot < CAP)
                        cand[(size_t)row * CAP + slot] = (ushort_t)(c0 + (cf << 4) + lr);
                }
            }
        }
    }
}

// ---------------- phase 2: exact fp32-chain verdict on candidates ----------
__global__ __launch_bounds__(256)
void vq_exact_kernel(const float* __restrict__ p0, const float* __restrict__ p1,
                     const int* __restrict__ flag, const float* __restrict__ arow_g,
                     const unsigned* __restrict__ cnt, const ushort_t* __restrict__ cand,
                     ull_t* __restrict__ keys)
{
    const float* __restrict__ Z = (flag[0] == 0) ? p0 : p1;
    const float* __restrict__ E = (flag[0] == 0) ? p1 : p0;
    int g = blockIdx.x * 256 + threadIdx.x;
    int row = g >> 6;
    int lane = g & 63;
    if (row >= NROWS) return;
    const float A = arow_g[row];
    const size_t zb = (size_t)row * DIM;
    unsigned n = cnt[row];
    ull_t best = 0xFFFFFFFFFFFFFFFFull;
    if (n <= CAP) {
        if (lane < (int)n) {
            int c = cand[(size_t)row * CAP + lane];
            float acc = 0.f;
            for (int k = 0; k < DIM; k += 4) {
                float4 zv = *(const float4*)&Z[zb + k];
                float4 ev = *(const float4*)&E[(size_t)c * DIM + k];
                acc = __fmaf_rn(zv.x, ev.x, acc);
                acc = __fmaf_rn(zv.y, ev.y, acc);
                acc = __fmaf_rn(zv.z, ev.z, acc);
                acc = __fmaf_rn(zv.w, ev.w, acc);
            }
            float d = __fsub_rn(A, __fmul_rn(2.0f, acc));
            best = ((ull_t)__float_as_uint(d) << 16) | (unsigned)c;
        }
    } else {
        for (int c = lane; c < NCODES; c += 64) {
            float acc = 0.f;
            for (int k = 0; k < DIM; k += 4) {
                float4 zv = *(const float4*)&Z[zb + k];
                float4 ev = *(const float4*)&E[(size_t)c * DIM + k];
                acc = __fmaf_rn(zv.x, ev.x, acc);
                acc = __fmaf_rn(zv.y, ev.y, acc);
                acc = __fmaf_rn(zv.z, ev.z, acc);
                acc = __fmaf_rn(zv.w, ev.w, acc);
            }
            float d = __fsub_rn(A, __fmul_rn(2.0f, acc));
            ull_t key = ((ull_t)__float_as_uint(d) << 16) | (unsigned)c;
            best = key < best ? key : best;
        }
    }
    #pragma unroll
    for (int m_ = 32; m_ >= 1; m_ >>= 1) {
        ull_t o = __shfl_xor(best, m_);
        best = o < best ? o : best;
    }
    if (lane == 0) keys[row] = best;
}

// ---------------- FALLBACK (ws too small): round-12 exact path ----------------
#define BM 128
#define BN 128
#define BK 32
#define NSPLIT 16
#define CSPLIT (NCODES / NSPLIT)
#define JT_PER (CSPLIT / BN)
#define KB_PER (DIM / BK)
#define NT (JT_PER * KB_PER)

__global__ __launch_bounds__(256)
void vq_keys_init(ull_t* __restrict__ keys)
{
    int i = blockIdx.x * 256 + threadIdx.x;
    if (i < NROWS) keys[i] = 0xFFFFFFFFFFFFFFFFull;
}

__global__ __launch_bounds__(256, 1)
void vq_argmin_kernel(const float* __restrict__ p0, const float* __restrict__ p1,
                      const int* __restrict__ flag, const float* __restrict__ arow_g,
                      ull_t* __restrict__ keys)
{
    const float* __restrict__ Z = (flag[0] == 0) ? p0 : p1;
    const float* __restrict__ E = (flag[0] == 0) ? p1 : p0;

    __shared__ float esb[2][BN * BK];
    __shared__ float arow_s[BM];

    const int tid = threadIdx.x;
    const int tx = tid & 15;
    const int ty = tid >> 4;
    const int wid = tid >> 6;
    const int lane = tid & 63;
    const int row0 = blockIdx.x * BM;
    const int c_base = blockIdx.y * CSPLIT;

    if (tid < BM) arow_s[tid] = arow_g[row0 + tid];

    const int fg = (lane & 7) ^ (lane >> 3);
    int elo[4];
    #pragma unroll
    for (int q = 0; q < 4; ++q) {
        const int ch = (wid << 2) + q;
        const int r = ch * 8 + (lane >> 3);
        elo[q] = r * DIM + fg * 4;
    }
    const int swe = (tx & 7) << 2;

    int zoff[8];
    #pragma unroll
    for (int i = 0; i < 8; ++i) zoff[i] = (row0 + ty + 16 * i) * DIM;

#define VQF_STAGE(BB, TT)                                                     \
    do {                                                                      \
        const int jn_ = (TT) >> 3;                                            \
        const int kn_ = (TT) & 7;                                             \
        const float* et_ = E + (size_t)(c_base + jn_ * BN) * DIM + kn_ * BK;  \
        _Pragma("unroll")                                                     \
        for (int q_ = 0; q_ < 4; ++q_) {                                      \
            const int ch_ = (wid << 2) + q_;                                  \
            __builtin_amdgcn_global_load_lds(                                 \
                (gas_t*)(et_ + elo[q_]), (las_t*)&esb[BB][ch_ << 8], 16, 0, 0);\
        }                                                                     \
    } while (0)

#define VQF_COMPUTE(BB, KN)                                                   \
    _Pragma("unroll 1")                                                       \
    for (int w_ = 0; w_ < 8; ++w_) {                                          \
        const int eo_ = ((w_ << 2) ^ swe);                                    \
        const int zk_ = (KN) * BK + (w_ << 2);                                \
        float4 ev[8];                                                         \
        _Pragma("unroll")                                                     \
        for (int j = 0; j < 8; ++j)                                           \
            ev[j] = *(const float4*)&esb[BB][((tx + 16 * j) << 5) + eo_];     \
        _Pragma("unroll")                                                     \
        for (int i = 0; i < 8; ++i) {                                         \
            float4 zv = *(const float4*)&Z[zoff[i] + zk_];                    \
            _Pragma("unroll")                                                 \
            for (int j = 0; j < 8; ++j) {                                     \
                acc[i][j] = __fmaf_rn(zv.x, ev[j].x, acc[i][j]);              \
                acc[i][j] = __fmaf_rn(zv.y, ev[j].y, acc[i][j]);              \
                acc[i][j] = __fmaf_rn(zv.z, ev[j].z, acc[i][j]);              \
                acc[i][j] = __fmaf_rn(zv.w, ev[j].w, acc[i][j]);              \
            }                                                                 \
        }                                                                     \
    }

    VQF_STAGE(0, 0);
    __syncthreads();

    float arow_r[8];
    #pragma unroll
    for (int i = 0; i < 8; ++i) arow_r[i] = arow_s[ty + 16 * i];

    float bestV[8];
    int bestI[8];
    #pragma unroll
    for (int i = 0; i < 8; ++i) { bestV[i] = 3.4e38f; bestI[i] = 0; }

    #pragma unroll 1
    for (int jt = 0; jt < JT_PER; ++jt) {
        const int c0 = c_base + jt * BN;
        float acc[8][8];
        #pragma unroll
        for (int i = 0; i < 8; ++i)
            #pragma unroll
            for (int j = 0; j < 8; ++j) acc[i][j] = 0.0f;

        #pragma unroll 1
        for (int kb2 = 0; kb2 < KB_PER / 2; ++kb2) {
            const int t0 = jt * KB_PER + kb2 * 2;
            VQF_STAGE(1, t0 + 1);
            VQF_COMPUTE(0, (t0 & 7))
            __syncthreads();
            if (t0 + 2 < NT) VQF_STAGE(0, t0 + 2);
            VQF_COMPUTE(1, ((t0 + 1) & 7))
            __syncthreads();
        }

        #pragma unroll
        for (int j = 0; j < 8; ++j) {
            int c = c0 + tx + 16 * j;
            #pragma unroll
            for (int i = 0; i < 8; ++i) {
                float dd = __fsub_rn(arow_r[i], __fmul_rn(2.0f, acc[i][j]));
                if (dd < bestV[i]) { bestV[i] = dd; bestI[i] = c; }
            }
        }
    }

    __syncthreads();
    float* rv = &esb[0][0];
    int* ri = (int*)&esb[1][0];
    #pragma unroll
    for (int i = 0; i < 8; ++i) {
        int r = ty + 16 * i;
        rv[r * 16 + tx] = bestV[i];
        ri[r * 16 + tx] = bestI[i];
    }
    __syncthreads();
    if (tid < BM) {
        float bv = rv[tid * 16];
        int bi = ri[tid * 16];
        for (int t = 1; t < 16; ++t) {
            float v = rv[tid * 16 + t];
            int ix = ri[tid * 16 + t];
            if (v < bv || (v == bv && ix < bi)) { bv = v; bi = ix; }
        }
        ull_t key = ((ull_t)__float_as_uint(bv) << 16) | (unsigned)bi;
        atomicMin(&keys[row0 + tid], key);
    }
}

// ---------------- gather z_q, loss partials, float indices ----------------
__global__ __launch_bounds__(256)
void vq_gather_kernel(const float* __restrict__ p0, const float* __restrict__ p1,
                      const int* __restrict__ flag, const ull_t* __restrict__ keys,
                      float* __restrict__ out_zq, float* __restrict__ out_idx_f,
                      double* __restrict__ partials)
{
    const float* __restrict__ Z = (flag[0] == 0) ? p0 : p1;
    const float* __restrict__ E = (flag[0] == 0) ? p1 : p0;

    const int tid = threadIdx.x;
    const int row0 = blockIdx.x * 64;
    double lsum = 0.0;
    for (int r = 0; r < 64; ++r) {
        int row = row0 + r;
        int id = (int)(keys[row] & 0xFFFFull);
        float e = E[(size_t)id * DIM + tid];
        float z = Z[(size_t)row * DIM + tid];
        out_zq[(size_t)row * DIM + tid] = e;
        double d = (double)e - (double)z;
        lsum += d * d;
    }
    __shared__ double red[256];
    red[tid] = lsum;
    __syncthreads();
    for (int s = 128; s > 0; s >>= 1) {
        if (tid < s) red[tid] += red[tid + s];
        __syncthreads();
    }
    if (tid == 0) partials[blockIdx.x] = red[0];
    if (tid < 64) out_idx_f[row0 + tid] = (float)(keys[row0 + tid] & 0xFFFFull);
}

__global__ void vq_loss_final(const double* __restrict__ partials, float* __restrict__ out_loss)
{
    const int tid = threadIdx.x;
    __shared__ double red[256];
    red[tid] = partials[tid];
    __syncthreads();
    for (int s = 128; s > 0; s >>= 1) {
        if (tid < s) red[tid] += red[tid + s];
        __syncthreads();
    }
    if (tid == 0) {
        double m = red[0] / ((double)NROWS * (double)DIM);
        out_loss[0] = (float)(1.25 * m);
    }
}

extern "C" void kernel_launch(void* const* d_in, const int* in_sizes, int n_in,
                              void* d_out, int out_size, void* d_ws, size_t ws_size,
                              hipStream_t stream)
{
    const float* p0 = (const float*)d_in[0];
    const float* p1 = (const float*)d_in[1];
    float* out = (float*)d_out;
    float* out_zq   = out;
    float* out_loss = out + 4194304;
    float* out_idxf = out + 4194305;

    const size_t NEED = 21301376;
    if (ws_size >= NEED) {
        // new-path ws layout
        ushort_t* zbf   = (ushort_t*)d_ws;                              // 8 MB
        ushort_t* ebf   = (ushort_t*)((char*)d_ws + 8388608);           // 8 MB
        float*    arow  = (float*)((char*)d_ws + 16777216);             // 64 KB
        ull_t*    keys  = (ull_t*)((char*)d_ws + 16842752);             // 128 KB
        unsigned* gmin  = (unsigned*)((char*)d_ws + 16973824);          // 64 KB
        unsigned* cnt   = (unsigned*)((char*)d_ws + 17039360);          // 64 KB
        unsigned* emax  = (unsigned*)((char*)d_ws + 17104896);          // 64 B
        int*      flag  = (int*)((char*)d_ws + 17104960);               // 64 B
        double*   parts = (double*)((char*)d_ws + 17105024);            // 2 KB
        ushort_t* cand  = (ushort_t*)((char*)d_ws + 17107072);          // 4 MB

        vq_which_kernel   <<<1, 256, 0, stream>>>(p0, p1, flag);
        vq_reset_kernel   <<<64, 256, 0, stream>>>(gmin, cnt, emax);
        vq_convert_kernel <<<4096, 256, 0, stream>>>(p0, p1, flag, zbf, ebf);
        vq_arow_kernel    <<<NROWS / AR_ROWS, 256, 0, stream>>>(p0, p1, flag, arow);
        vq_enorm_kernel   <<<NCODES / 4, 256, 0, stream>>>(p0, p1, flag, emax);
        {
            dim3 grid(NROWS / 256, NCODES / 128);
            vq_mfma_kernel <<<grid, 256, 0, stream>>>(zbf, ebf, arow, emax, gmin, cnt, cand);
        }
        vq_exact_kernel  <<<(NROWS * 64 + 255) / 256, 256, 0, stream>>>(p0, p1, flag, arow, cnt, cand, keys);
        vq_gather_kernel <<<NROWS / 64, 256, 0, stream>>>(p0, p1, flag, keys, out_zq, out_idxf, parts);
        vq_loss_final    <<<1, 256, 0, stream>>>(parts, out_loss);
    } else {
        // fallback: round-12 exact path
        ull_t*  keys     = (ull_t*)d_ws;
        float*  arow     = (float*)((char*)d_ws + 131072);
        double* parts    = (double*)((char*)d_ws + 131072 + 65536);
        int*    flag     = (int*)((char*)d_ws + 131072 + 65536 + 2048);

        vq_which_kernel <<<1, 256, 0, stream>>>(p0, p1, flag);
        vq_arow_kernel  <<<NROWS / AR_ROWS, 256, 0, stream>>>(p0, p1, flag, arow);
        vq_keys_init    <<<NROWS / 256, 256, 0, stream>>>(keys);
        {
            dim3 grid(NROWS / BM, NSPLIT);
            vq_argmin_kernel <<<grid, 256, 0, stream>>>(p0, p1, flag, arow, keys);
        }
        vq_gather_kernel <<<NROWS / 64, 256, 0, stream>>>(p0, p1, flag, keys, out_zq, out_idxf, parts);
        vq_loss_final    <<<1, 256, 0, stream>>>(parts, out_loss);
    }
}

// Round 19
// 655.084 us; speedup vs baseline: 5.2450x; 5.2450x over previous
//
#include <hip/hip_runtime.h>
#include <stdint.h>

#define NROWS 16384
#define NCODES 16384
#define DIM 256
#define CAP 128

typedef unsigned short ushort_t;
typedef unsigned long long ull_t;
typedef __attribute__((ext_vector_type(8))) short bf16x8;
typedef __attribute__((ext_vector_type(4))) float f32x4;
typedef __attribute__((address_space(1))) const void gas_t;
typedef __attribute__((address_space(3))) void las_t;

// ---------------- which input is z? (z ~ N(0,1), emb ~ N(0,1)/16384) ----------------
__global__ __launch_bounds__(256)
void vq_which_kernel(const float* __restrict__ p0, const float* __restrict__ p1,
                     int* __restrict__ flag)
{
    __shared__ float red[256];
    const int tid = threadIdx.x;
    float s = 0.f;
    for (int t = tid; t < 4096; t += 256) s += fabsf(p0[t]) - fabsf(p1[t]);
    red[tid] = s;
    __syncthreads();
    for (int k = 128; k > 0; k >>= 1) {
        if (tid < k) red[tid] += red[tid + k];
        __syncthreads();
    }
    if (tid == 0) flag[0] = (red[0] >= 0.f) ? 0 : 1;   // 0: p0 is z
}

// numpy pairwise fp32 sum of squares of a 256-float row (exact numpy order).
__device__ __forceinline__ float np_pairwise_sumsq256(const float* __restrict__ a)
{
    float H[2];
    #pragma unroll
    for (int h = 0; h < 2; ++h) {
        const float* p = a + h * 128;
        float r[8];
        #pragma unroll
        for (int j = 0; j < 8; ++j) r[j] = __fmul_rn(p[j], p[j]);
        for (int i = 8; i < 128; i += 8) {
            #pragma unroll
            for (int j = 0; j < 8; ++j)
                r[j] = __fadd_rn(r[j], __fmul_rn(p[i + j], p[i + j]));
        }
        H[h] = __fadd_rn(__fadd_rn(__fadd_rn(r[0], r[1]), __fadd_rn(r[2], r[3])),
                         __fadd_rn(__fadd_rn(r[4], r[5]), __fadd_rn(r[6], r[7])));
    }
    return __fadd_rn(H[0], H[1]);
}

// ---------------- per-row ||z||^2 in exact numpy order ----------------
#define AR_ROWS 32
#define AR_STR 260
__global__ __launch_bounds__(256)
void vq_arow_kernel(const float* __restrict__ p0, const float* __restrict__ p1,
                    const int* __restrict__ flag, float* __restrict__ arow_g)
{
    const float* __restrict__ Z = (flag[0] == 0) ? p0 : p1;
    __shared__ float ls[AR_ROWS * AR_STR];
    const int tid = threadIdx.x;
    const int row0 = blockIdx.x * AR_ROWS;
    #pragma unroll
    for (int q = 0; q < 8; ++q) {
        int f4 = tid + 256 * q;
        int r = f4 >> 6;
        int c = (f4 & 63) << 2;
        *(float4*)&ls[r * AR_STR + c] =
            *(const float4*)&Z[(size_t)(row0 + r) * DIM + c];
    }
    __syncthreads();
    if (tid < AR_ROWS) arow_g[row0 + tid] = np_pairwise_sumsq256(&ls[tid * AR_STR]);
}

// ---------------- reset: gmin=FLT_MAX, cnt=0, emax=0 ----------------
__global__ __launch_bounds__(256)
void vq_reset_kernel(unsigned* __restrict__ gmin, unsigned* __restrict__ cnt,
                     unsigned* __restrict__ emax)
{
    int i = blockIdx.x * 256 + threadIdx.x;
    if (i < NROWS) { gmin[i] = 0x7F7FFFFFu; cnt[i] = 0u; }
    if (i == 0) emax[0] = 0u;
}

// ---------------- fp32 -> bf16 (RNE) copies of both inputs ----------------
__device__ __forceinline__ ushort_t f2bf(float x)
{
    unsigned u = __float_as_uint(x);
    return (ushort_t)((u + 0x7FFFu + ((u >> 16) & 1u)) >> 16);
}
__global__ __launch_bounds__(256)
void vq_convert_kernel(const float* __restrict__ p0, const float* __restrict__ p1,
                       const int* __restrict__ flag,
                       ushort_t* __restrict__ zbf, ushort_t* __restrict__ ebf)
{
    const float* __restrict__ Z = (flag[0] == 0) ? p0 : p1;
    const float* __restrict__ E = (flag[0] == 0) ? p1 : p0;
    size_t i = ((size_t)blockIdx.x * 256 + threadIdx.x) * 4;
    if (i >= (size_t)NROWS * DIM) return;
    float4 z4 = *(const float4*)&Z[i];
    float4 e4 = *(const float4*)&E[i];
    ushort4 zo = { f2bf(z4.x), f2bf(z4.y), f2bf(z4.z), f2bf(z4.w) };
    ushort4 eo = { f2bf(e4.x), f2bf(e4.y), f2bf(e4.z), f2bf(e4.w) };
    *(ushort4*)&zbf[i] = zo;
    *(ushort4*)&ebf[i] = eo;
}

// ---------------- max code L2 norm (for the rigorous margin) ----------------
__global__ __launch_bounds__(256)
void vq_enorm_kernel(const float* __restrict__ p0, const float* __restrict__ p1,
                     const int* __restrict__ flag, unsigned* __restrict__ emax)
{
    const float* __restrict__ E = (flag[0] == 0) ? p1 : p0;
    int wave = (blockIdx.x * blockDim.x + threadIdx.x) >> 6;
    int lane = threadIdx.x & 63;
    if (wave >= NCODES) return;
    float4 v = *(const float4*)&E[(size_t)wave * DIM + lane * 4];
    float s = v.x * v.x + v.y * v.y + v.z * v.z + v.w * v.w;
    #pragma unroll
    for (int off = 32; off > 0; off >>= 1) s += __shfl_down(s, off);
    if (lane == 0) atomicMax(emax, __float_as_uint(sqrtf(s)));
}

// ---------------- phase 1: bf16 MFMA distance sweep + candidate capture ------
// ROUND-19: exact REVERT to the round-16 kernel (verified absmax 0.0 incl.
// post-timing replays, 655 us total). Rounds 17/18's 256x128 restructure
// produced a replay-only divergence twice that is not isolable by inspection
// — abandoned per rigor discipline.
// Staging via global_load_lds DMA into LINEAR [128][128] bf16 rows with
// both-sides XOR chunk swizzle:
//   DMA group = 1KB = 4 rows x 16 chunks; lane l -> row 4g+(l>>4),
//   SOURCE chunk (l&15)^(r&7); LDS linear => LDS[r][c] = G[r][c^(r&7)].
//   Reads at chunk (kc*4+lk)^(lr&7) => G[r][kc*4+lk].
// K-order per accumulator (kh up, kc up, lane-k ascending) == rounds 13/15 ->
// approx distances BIT-IDENTICAL; capture margins unchanged.
// A/B frag: lane&15 = row/col, k = (lane>>4)*8+elem. C/D: col=lane&15,
// row=(lane>>4)*4+reg [verified m89 + rounds 13/15/16 absmax 0.0].
__global__ __launch_bounds__(256, 1)
void vq_mfma_kernel(const ushort_t* __restrict__ zbf, const ushort_t* __restrict__ ebf,
                    const float* __restrict__ arow_g, const unsigned* __restrict__ emax,
                    unsigned* __restrict__ gmin, unsigned* __restrict__ cnt,
                    ushort_t* __restrict__ cand)
{
    __shared__ ushort_t zs[128 * 128];   // 32 KB, K-half, swizzled chunks
    __shared__ ushort_t es[128 * 128];
    const int tid = threadIdx.x;
    const int row0 = blockIdx.x * 128;
    const int c0   = blockIdx.y * 128;

    const int w  = tid >> 6;
    const int l  = tid & 63;
    const int lr = l & 15;
    const int lk = l >> 4;

    // DMA source offsets: wave w fills groups g = w*8+q (q=0..7) per array.
    int zlo[8], elo[8];
    #pragma unroll
    for (int q = 0; q < 8; ++q) {
        const int g = w * 8 + q;
        const int r = 4 * g + (l >> 4);
        const int sl = (l & 15) ^ (4 * (q & 1) + (l >> 4));   // (l&15)^(r&7)
        zlo[q] = (row0 + r) * DIM + sl * 8;
        elo[q] = (c0 + r) * DIM + sl * 8;
    }

    f32x4 acc[2][8];
    #pragma unroll
    for (int rf = 0; rf < 2; ++rf)
        #pragma unroll
        for (int cf = 0; cf < 8; ++cf) acc[rf][cf] = (f32x4){0.f, 0.f, 0.f, 0.f};

    #pragma unroll 1
    for (int kh = 0; kh < 2; ++kh) {
        __syncthreads();   // previous half fully consumed (no-op at kh=0)
        #pragma unroll
        for (int q = 0; q < 8; ++q) {
            const int g = w * 8 + q;
            __builtin_amdgcn_global_load_lds(
                (gas_t*)(zbf + zlo[q] + kh * 128), (las_t*)&zs[g * 512], 16, 0, 0);
            __builtin_amdgcn_global_load_lds(
                (gas_t*)(ebf + elo[q] + kh * 128), (las_t*)&es[g * 512], 16, 0, 0);
        }
        __syncthreads();   // vmcnt drain: DMA data visible
        #pragma unroll 1
        for (int kc = 0; kc < 4; ++kc) {
            const int sz = ((kc * 4 + lk) ^ (lr & 7)) * 8;   // swizzled ushort offset
            bf16x8 a0 = *(const bf16x8*)&zs[(w * 32 + lr) * 128 + sz];
            bf16x8 a1 = *(const bf16x8*)&zs[(w * 32 + 16 + lr) * 128 + sz];
            #pragma unroll
            for (int cf = 0; cf < 8; ++cf) {
                bf16x8 b = *(const bf16x8*)&es[(cf * 16 + lr) * 128 + sz];
                acc[0][cf] = __builtin_amdgcn_mfma_f32_16x16x32_bf16(a0, b, acc[0][cf], 0, 0, 0);
                acc[1][cf] = __builtin_amdgcn_mfma_f32_16x16x32_bf16(a1, b, acc[1][cf], 0, 0, 0);
            }
        }
    }

    const float emaxv = __uint_as_float(emax[0]);
    float Av[8], rm[8];
    #pragma unroll
    for (int rf = 0; rf < 2; ++rf)
        #pragma unroll
        for (int reg = 0; reg < 4; ++reg)
            Av[rf * 4 + reg] = arow_g[row0 + w * 32 + rf * 16 + lk * 4 + reg];

    #pragma unroll
    for (int rf = 0; rf < 2; ++rf)
        #pragma unroll
        for (int reg = 0; reg < 4; ++reg) {
            int p = rf * 4 + reg;
            float mn = 3.4e38f;
            #pragma unroll
            for (int cf = 0; cf < 8; ++cf) {
                float d = __fsub_rn(Av[p], __fmul_rn(2.0f, acc[rf][cf][reg]));
                acc[rf][cf][reg] = d;
                mn = fminf(mn, d);
            }
            rm[p] = mn;
        }
    #pragma unroll
    for (int m_ = 1; m_ < 16; m_ <<= 1)
        #pragma unroll
        for (int p = 0; p < 8; ++p)
            rm[p] = fminf(rm[p], __shfl_xor(rm[p], m_));

    if (lr == 0) {
        #pragma unroll
        for (int p = 0; p < 8; ++p) {
            int row = row0 + w * 32 + (p >> 2) * 16 + lk * 4 + (p & 3);
            atomicMin(&gmin[row], __float_as_uint(rm[p]));
        }
    }

    float th[8];
    #pragma unroll
    for (int p = 0; p < 8; ++p) {
        int row = row0 + w * 32 + (p >> 2) * 16 + lk * 4 + (p & 3);
        float g = __uint_as_float(gmin[row]);   // stale => larger => safe
        float m = 0.036f * sqrtf(Av[p]) * emaxv + 1.5e-4f;
        th[p] = fminf(g, rm[p]) + m;
    }

    #pragma unroll
    for (int rf = 0; rf < 2; ++rf)
        #pragma unroll
        for (int reg = 0; reg < 4; ++reg) {
            int p = rf * 4 + reg;
            int row = row0 + w * 32 + rf * 16 + lk * 4 + reg;
            #pragma unroll
            for (int cf = 0; cf < 8; ++cf) {
                if (acc[rf][cf][reg] <= th[p]) {
                    unsigned slot = atomicAdd(&cnt[row], 1u);
                    if (slot < CAP)
                        cand[(size_t)row * CAP + slot] = (ushort_t)(c0 + cf * 16 + lr);
                }
            }
        }
}

// ---------------- phase 2: exact fp32-chain verdict on candidates ----------
__global__ __launch_bounds__(256)
void vq_exact_kernel(const float* __restrict__ p0, const float* __restrict__ p1,
                     const int* __restrict__ flag, const float* __restrict__ arow_g,
                     const unsigned* __restrict__ cnt, const ushort_t* __restrict__ cand,
                     ull_t* __restrict__ keys)
{
    const float* __restrict__ Z = (flag[0] == 0) ? p0 : p1;
    const float* __restrict__ E = (flag[0] == 0) ? p1 : p0;
    int g = blockIdx.x * 256 + threadIdx.x;
    int row = g >> 6;
    int lane = g & 63;
    if (row >= NROWS) return;
    const float A = arow_g[row];
    const size_t zb = (size_t)row * DIM;
    unsigned n = cnt[row];
    ull_t best = 0xFFFFFFFFFFFFFFFFull;
    if (n <= CAP) {
        if (lane < (int)n) {
            int c = cand[(size_t)row * CAP + lane];
            float acc = 0.f;
            for (int k = 0; k < DIM; k += 4) {
                float4 zv = *(const float4*)&Z[zb + k];
                float4 ev = *(const float4*)&E[(size_t)c * DIM + k];
                acc = __fmaf_rn(zv.x, ev.x, acc);
                acc = __fmaf_rn(zv.y, ev.y, acc);
                acc = __fmaf_rn(zv.z, ev.z, acc);
                acc = __fmaf_rn(zv.w, ev.w, acc);
            }
            float d = __fsub_rn(A, __fmul_rn(2.0f, acc));
            best = ((ull_t)__float_as_uint(d) << 16) | (unsigned)c;
        }
    } else {
        for (int c = lane; c < NCODES; c += 64) {
            float acc = 0.f;
            for (int k = 0; k < DIM; k += 4) {
                float4 zv = *(const float4*)&Z[zb + k];
                float4 ev = *(const float4*)&E[(size_t)c * DIM + k];
                acc = __fmaf_rn(zv.x, ev.x, acc);
                acc = __fmaf_rn(zv.y, ev.y, acc);
                acc = __fmaf_rn(zv.z, ev.z, acc);
                acc = __fmaf_rn(zv.w, ev.w, acc);
            }
            float d = __fsub_rn(A, __fmul_rn(2.0f, acc));
            ull_t key = ((ull_t)__float_as_uint(d) << 16) | (unsigned)c;
            best = key < best ? key : best;
        }
    }
    #pragma unroll
    for (int m_ = 32; m_ >= 1; m_ >>= 1) {
        ull_t o = __shfl_xor(best, m_);
        best = o < best ? o : best;
    }
    if (lane == 0) keys[row] = best;
}

// ---------------- FALLBACK (ws too small): round-12 exact path ----------------
#define BM 128
#define BN 128
#define BK 32
#define NSPLIT 16
#define CSPLIT (NCODES / NSPLIT)
#define JT_PER (CSPLIT / BN)
#define KB_PER (DIM / BK)
#define NT (JT_PER * KB_PER)

__global__ __launch_bounds__(256)
void vq_keys_init(ull_t* __restrict__ keys)
{
    int i = blockIdx.x * 256 + threadIdx.x;
    if (i < NROWS) keys[i] = 0xFFFFFFFFFFFFFFFFull;
}

__global__ __launch_bounds__(256, 1)
void vq_argmin_kernel(const float* __restrict__ p0, const float* __restrict__ p1,
                      const int* __restrict__ flag, const float* __restrict__ arow_g,
                      ull_t* __restrict__ keys)
{
    const float* __restrict__ Z = (flag[0] == 0) ? p0 : p1;
    const float* __restrict__ E = (flag[0] == 0) ? p1 : p0;

    __shared__ float esb[2][BN * BK];
    __shared__ float arow_s[BM];

    const int tid = threadIdx.x;
    const int tx = tid & 15;
    const int ty = tid >> 4;
    const int wid = tid >> 6;
    const int lane = tid & 63;
    const int row0 = blockIdx.x * BM;
    const int c_base = blockIdx.y * CSPLIT;

    if (tid < BM) arow_s[tid] = arow_g[row0 + tid];

    const int fg = (lane & 7) ^ (lane >> 3);
    int elo[4];
    #pragma unroll
    for (int q = 0; q < 4; ++q) {
        const int ch = (wid << 2) + q;
        const int r = ch * 8 + (lane >> 3);
        elo[q] = r * DIM + fg * 4;
    }
    const int swe = (tx & 7) << 2;

    int zoff[8];
    #pragma unroll
    for (int i = 0; i < 8; ++i) zoff[i] = (row0 + ty + 16 * i) * DIM;

#define VQF_STAGE(BB, TT)                                                     \
    do {                                                                      \
        const int jn_ = (TT) >> 3;                                            \
        const int kn_ = (TT) & 7;                                             \
        const float* et_ = E + (size_t)(c_base + jn_ * BN) * DIM + kn_ * BK;  \
        _Pragma("unroll")                                                     \
        for (int q_ = 0; q_ < 4; ++q_) {                                      \
            const int ch_ = (wid << 2) + q_;                                  \
            __builtin_amdgcn_global_load_lds(                                 \
                (gas_t*)(et_ + elo[q_]), (las_t*)&esb[BB][ch_ << 8], 16, 0, 0);\
        }                                                                     \
    } while (0)

#define VQF_COMPUTE(BB, KN)                                                   \
    _Pragma("unroll 1")                                                       \
    for (int w_ = 0; w_ < 8; ++w_) {                                          \
        const int eo_ = ((w_ << 2) ^ swe);                                    \
        const int zk_ = (KN) * BK + (w_ << 2);                                \
        float4 ev[8];                                                         \
        _Pragma("unroll")                                                     \
        for (int j = 0; j < 8; ++j)                                           \
            ev[j] = *(const float4*)&esb[BB][((tx + 16 * j) << 5) + eo_];     \
        _Pragma("unroll")                                                     \
        for (int i = 0; i < 8; ++i) {                                         \
            float4 zv = *(const float4*)&Z[zoff[i] + zk_];                    \
            _Pragma("unroll")                                                 \
            for (int j = 0; j < 8; ++j) {                                     \
                acc[i][j] = __fmaf_rn(zv.x, ev[j].x, acc[i][j]);              \
                acc[i][j] = __fmaf_rn(zv.y, ev[j].y, acc[i][j]);              \
                acc[i][j] = __fmaf_rn(zv.z, ev[j].z, acc[i][j]);              \
                acc[i][j] = __fmaf_rn(zv.w, ev[j].w, acc[i][j]);              \
            }                                                                 \
        }                                                                     \
    }

    VQF_STAGE(0, 0);
    __syncthreads();

    float arow_r[8];
    #pragma unroll
    for (int i = 0; i < 8; ++i) arow_r[i] = arow_s[ty + 16 * i];

    float bestV[8];
    int bestI[8];
    #pragma unroll
    for (int i = 0; i < 8; ++i) { bestV[i] = 3.4e38f; bestI[i] = 0; }

    #pragma unroll 1
    for (int jt = 0; jt < JT_PER; ++jt) {
        const int c0 = c_base + jt * BN;
        float acc[8][8];
        #pragma unroll
        for (int i = 0; i < 8; ++i)
            #pragma unroll
            for (int j = 0; j < 8; ++j) acc[i][j] = 0.0f;

        #pragma unroll 1
        for (int kb2 = 0; kb2 < KB_PER / 2; ++kb2) {
            const int t0 = jt * KB_PER + kb2 * 2;
            VQF_STAGE(1, t0 + 1);
            VQF_COMPUTE(0, (t0 & 7))
            __syncthreads();
            if (t0 + 2 < NT) VQF_STAGE(0, t0 + 2);
            VQF_COMPUTE(1, ((t0 + 1) & 7))
            __syncthreads();
        }

        #pragma unroll
        for (int j = 0; j < 8; ++j) {
            int c = c0 + tx + 16 * j;
            #pragma unroll
            for (int i = 0; i < 8; ++i) {
                float dd = __fsub_rn(arow_r[i], __fmul_rn(2.0f, acc[i][j]));
                if (dd < bestV[i]) { bestV[i] = dd; bestI[i] = c; }
            }
        }
    }

    __syncthreads();
    float* rv = &esb[0][0];
    int* ri = (int*)&esb[1][0];
    #pragma unroll
    for (int i = 0; i < 8; ++i) {
        int r = ty + 16 * i;
        rv[r * 16 + tx] = bestV[i];
        ri[r * 16 + tx] = bestI[i];
    }
    __syncthreads();
    if (tid < BM) {
        float bv = rv[tid * 16];
        int bi = ri[tid * 16];
        for (int t = 1; t < 16; ++t) {
            float v = rv[tid * 16 + t];
            int ix = ri[tid * 16 + t];
            if (v < bv || (v == bv && ix < bi)) { bv = v; bi = ix; }
        }
        ull_t key = ((ull_t)__float_as_uint(bv) << 16) | (unsigned)bi;
        atomicMin(&keys[row0 + tid], key);
    }
}

// ---------------- gather z_q, loss partials, float indices ----------------
__global__ __launch_bounds__(256)
void vq_gather_kernel(const float* __restrict__ p0, const float* __restrict__ p1,
                      const int* __restrict__ flag, const ull_t* __restrict__ keys,
                      float* __restrict__ out_zq, float* __restrict__ out_idx_f,
                      double* __restrict__ partials)
{
    const float* __restrict__ Z = (flag[0] == 0) ? p0 : p1;
    const float* __restrict__ E = (flag[0] == 0) ? p1 : p0;

    const int tid = threadIdx.x;
    const int row0 = blockIdx.x * 64;
    double lsum = 0.0;
    for (int r = 0; r < 64; ++r) {
        int row = row0 + r;
        int id = (int)(keys[row] & 0xFFFFull);
        float e = E[(size_t)id * DIM + tid];
        float z = Z[(size_t)row * DIM + tid];
        out_zq[(size_t)row * DIM + tid] = e;
        double d = (double)e - (double)z;
        lsum += d * d;
    }
    __shared__ double red[256];
    red[tid] = lsum;
    __syncthreads();
    for (int s = 128; s > 0; s >>= 1) {
        if (tid < s) red[tid] += red[tid + s];
        __syncthreads();
    }
    if (tid == 0) partials[blockIdx.x] = red[0];
    if (tid < 64) out_idx_f[row0 + tid] = (float)(keys[row0 + tid] & 0xFFFFull);
}

__global__ void vq_loss_final(const double* __restrict__ partials, float* __restrict__ out_loss)
{
    const int tid = threadIdx.x;
    __shared__ double red[256];
    red[tid] = partials[tid];
    __syncthreads();
    for (int s = 128; s > 0; s >>= 1) {
        if (tid < s) red[tid] += red[tid + s];
        __syncthreads();
    }
    if (tid == 0) {
        double m = red[0] / ((double)NROWS * (double)DIM);
        out_loss[0] = (float)(1.25 * m);
    }
}

extern "C" void kernel_launch(void* const* d_in, const int* in_sizes, int n_in,
                              void* d_out, int out_size, void* d_ws, size_t ws_size,
                              hipStream_t stream)
{
    const float* p0 = (const float*)d_in[0];
    const float* p1 = (const float*)d_in[1];
    float* out = (float*)d_out;
    float* out_zq   = out;
    float* out_loss = out + 4194304;
    float* out_idxf = out + 4194305;

    const size_t NEED = 21301376;
    if (ws_size >= NEED) {
        // new-path ws layout
        ushort_t* zbf   = (ushort_t*)d_ws;                              // 8 MB
        ushort_t* ebf   = (ushort_t*)((char*)d_ws + 8388608);           // 8 MB
        float*    arow  = (float*)((char*)d_ws + 16777216);             // 64 KB
        ull_t*    keys  = (ull_t*)((char*)d_ws + 16842752);             // 128 KB
        unsigned* gmin  = (unsigned*)((char*)d_ws + 16973824);          // 64 KB
        unsigned* cnt   = (unsigned*)((char*)d_ws + 17039360);          // 64 KB
        unsigned* emax  = (unsigned*)((char*)d_ws + 17104896);          // 64 B
        int*      flag  = (int*)((char*)d_ws + 17104960);               // 64 B
        double*   parts = (double*)((char*)d_ws + 17105024);            // 2 KB
        ushort_t* cand  = (ushort_t*)((char*)d_ws + 17107072);          // 4 MB

        vq_which_kernel   <<<1, 256, 0, stream>>>(p0, p1, flag);
        vq_reset_kernel   <<<64, 256, 0, stream>>>(gmin, cnt, emax);
        vq_convert_kernel <<<4096, 256, 0, stream>>>(p0, p1, flag, zbf, ebf);
        vq_arow_kernel    <<<NROWS / AR_ROWS, 256, 0, stream>>>(p0, p1, flag, arow);
        vq_enorm_kernel   <<<NCODES / 4, 256, 0, stream>>>(p0, p1, flag, emax);
        {
            dim3 grid(NROWS / 128, NCODES / 128);
            vq_mfma_kernel <<<grid, 256, 0, stream>>>(zbf, ebf, arow, emax, gmin, cnt, cand);
        }
        vq_exact_kernel  <<<(NROWS * 64 + 255) / 256, 256, 0, stream>>>(p0, p1, flag, arow, cnt, cand, keys);
        vq_gather_kernel <<<NROWS / 64, 256, 0, stream>>>(p0, p1, flag, keys, out_zq, out_idxf, parts);
        vq_loss_final    <<<1, 256, 0, stream>>>(parts, out_loss);
    } else {
        // fallback: round-12 exact path
        ull_t*  keys     = (ull_t*)d_ws;
        float*  arow     = (float*)((char*)d_ws + 131072);
        double* parts    = (double*)((char*)d_ws + 131072 + 65536);
        int*    flag     = (int*)((char*)d_ws + 131072 + 65536 + 2048);

        vq_which_kernel <<<1, 256, 0, stream>>>(p0, p1, flag);
        vq_arow_kernel  <<<NROWS / AR_ROWS, 256, 0, stream>>>(p0, p1, flag, arow);
        vq_keys_init    <<<NROWS / 256, 256, 0, stream>>>(keys);
        {
            dim3 grid(NROWS / BM, NSPLIT);
            vq_argmin_kernel <<<grid, 256, 0, stream>>>(p0, p1, flag, arow, keys);
        }
        vq_gather_kernel <<<NROWS / 64, 256, 0, stream>>>(p0, p1, flag, keys, out_zq, out_idxf, parts);
        vq_loss_final    <<<1, 256, 0, stream>>>(parts, out_loss);
    }
}